// Round 5
// baseline (1351.872 us; speedup 1.0000x reference)
//
#include <hip/hip_runtime.h>
#include <math.h>

// Problem constants (match reference)
#define Bb   256
#define Tt   512
#define Vv   50000
#define Ee   300
#define Hh   128
#define G4   512          // 4*H
#define EPS  1e-12f
#define FBIAS 1.0f

typedef _Float16 half8 __attribute__((ext_vector_type(8)));
typedef float    f32x4 __attribute__((ext_vector_type(4)));

// ---------------------------------------------------------------------------
// Cross-lane helpers (DPP-only reductions)
// ---------------------------------------------------------------------------
template <int CTRL>
__device__ inline float dpp_mov(float v) {
    return __int_as_float(
        __builtin_amdgcn_update_dpp(0, __float_as_int(v), CTRL, 0xF, 0xF, true));
}
// sum over each 16-lane group
__device__ inline float red16(float v) {
    v += dpp_mov<0xB1>(v);    // quad_perm [1,0,3,2]
    v += dpp_mov<0x4E>(v);    // quad_perm [2,3,0,1]
    v += dpp_mov<0x141>(v);   // row_half_mirror
    v += dpp_mov<0x140>(v);   // row_mirror
    return v;
}
// sum over all 64 lanes, broadcast via readlane (pure VALU/DPP, no LDS)
__device__ inline float red64b(float v) {
    v = red16(v);
    v += dpp_mov<0x142>(v);   // row_bcast15
    v += dpp_mov<0x143>(v);   // row_bcast31  => lane63 holds total
    return __int_as_float(__builtin_amdgcn_readlane(__float_as_int(v), 63));
}

// barrier that drains only LDS counters (global prefetches float across)
__device__ inline void lds_barrier() {
    __builtin_amdgcn_sched_barrier(0);
    asm volatile("s_waitcnt lgkmcnt(0)" ::: "memory");
    __builtin_amdgcn_sched_barrier(0);
    __builtin_amdgcn_s_barrier();
    __builtin_amdgcn_sched_barrier(0);
}

__device__ inline float sigm(float v) {
    return __fdividef(1.0f, 1.0f + __expf(-v));
}

// ---------------------------------------------------------------------------
// Phase 1: P[v,:] = embed[v,:] @ W[0:E,:] via f16 MFMA (proven in round 4).
// ---------------------------------------------------------------------------
#define PROJ_TILES ((Vv + 31) / 32)

__global__ __launch_bounds__(512, 2) void embed_proj_mfma(
    const float* __restrict__ embed,   // [V, E]
    const float* __restrict__ W,       // [E+H, 4H]
    float* __restrict__ P)             // [V, 4H]
{
    __shared__ __align__(16) _Float16 A[32 * 320];   // 20 KB

    const int tid  = threadIdx.x;
    const int wv   = tid >> 6;
    const int lane = tid & 63;
    const int p16  = lane & 15;
    const int gq   = lane >> 4;

    // B-fragments: col = wv*64 + tt*16 + p16 ; k = ks*32 + gq*8 + j
    half8 bf[4][10];
    #pragma unroll
    for (int tt = 0; tt < 4; ++tt) {
        #pragma unroll
        for (int ks = 0; ks < 10; ++ks) {
            half8 h;
            #pragma unroll
            for (int j = 0; j < 8; ++j) {
                int k = ks * 32 + gq * 8 + j;
                h[j] = (k < Ee)
                     ? (_Float16)W[(size_t)k * G4 + wv * 64 + tt * 16 + p16]
                     : (_Float16)0.f;
            }
            bf[tt][ks] = h;
        }
    }

    char* const Ab = (char*)A;
    for (int i = tid; i < 32 * 10; i += 512) {
        int row = i / 10, m = i - row * 10;
        *(uint*)(Ab + ((row * 640 + 600 + m * 4) ^ ((row & 7) << 4))) = 0u;
    }
    __syncthreads();

    for (int mtile = blockIdx.x; mtile < PROJ_TILES; mtile += gridDim.x) {
        const int r0 = mtile * 32;

        for (int i = tid; i < 32 * 75; i += 512) {
            int row = i / 75, k4 = i - row * 75;
            int grow = r0 + row;
            float4 v = (grow < Vv) ? *(const float4*)&embed[(size_t)grow * Ee + k4 * 4]
                                   : (float4){0.f, 0.f, 0.f, 0.f};
            union { _Float16 h[4]; uint2 u; } pk;
            pk.h[0] = (_Float16)v.x; pk.h[1] = (_Float16)v.y;
            pk.h[2] = (_Float16)v.z; pk.h[3] = (_Float16)v.w;
            *(uint2*)(Ab + ((row * 640 + k4 * 8) ^ ((row & 7) << 4))) = pk.u;
        }
        __syncthreads();

        f32x4 acc[2][4];
        #pragma unroll
        for (int mt = 0; mt < 2; ++mt)
            #pragma unroll
            for (int tt = 0; tt < 4; ++tt)
                acc[mt][tt] = (f32x4){0.f, 0.f, 0.f, 0.f};

        #pragma unroll
        for (int mt = 0; mt < 2; ++mt) {
            const int arow = mt * 16 + p16;
            #pragma unroll
            for (int ks = 0; ks < 10; ++ks) {
                half8 af = *(const half8*)(Ab + ((arow * 640 + ks * 64 + gq * 16)
                                                 ^ ((arow & 7) << 4)));
                #pragma unroll
                for (int tt = 0; tt < 4; ++tt)
                    acc[mt][tt] = __builtin_amdgcn_mfma_f32_16x16x32_f16(
                        af, bf[tt][ks], acc[mt][tt], 0, 0, 0);
            }
        }

        #pragma unroll
        for (int mt = 0; mt < 2; ++mt)
            #pragma unroll
            for (int tt = 0; tt < 4; ++tt)
                #pragma unroll
                for (int r = 0; r < 4; ++r) {
                    int row = r0 + mt * 16 + gq * 4 + r;
                    if (row < Vv)
                        P[(size_t)row * G4 + wv * 64 + tt * 16 + p16] = acc[mt][tt][r];
                }
        __syncthreads();
    }
}

// ---------------------------------------------------------------------------
// Phase 2: 32 blocks x 8 rows. 8 waves = 2 teams x 4 waves, phase-shifted:
// interval i: team (i&1) does MFMA(z=h@Wh, step i>>1); other team does
// LN/cell (step (i-1)>>1). One barrier per interval. Teams overlap at
// 2 waves/SIMD, so MFMA of one team hides LN latency of the other.
//  - B-frags hdim-grouped: wave w owns hdims w*32..+31 for ALL 4 gates ->
//    phase-B lane reads i,j,f,o of its 2 hdims directly (no transpose pass).
//  - z staged [col][5] f32 (5-word pad): conflict-free write2/read2.
//  - gate-LN + cell-LN stats via pure-DPP red64b.
//  - P[x[row,t]] prefetched 2 intervals ahead (double-buffered regs).
// ---------------------------------------------------------------------------
#define RPT   4                       // rows per team
#define RPBLK 8                       // rows per block
#define LBLK  (Bb / RPBLK)            // 32 blocks

__global__ __launch_bounds__(512, 2) void lstm_mfma3(
    const float* __restrict__ P,       // [V, 4H]
    const float* __restrict__ W,       // [E+H, 4H]
    const int*   __restrict__ x,       // [B, T]
    const float* __restrict__ gains,   // [5, H]
    const float* __restrict__ shifts,  // [5, H]
    float* __restrict__ out)           // [B, T, H]
{
    __shared__ __align__(16) float    z5[2][G4 * 5];      // 20 KB  [team][col*5+r]
    __shared__ __align__(16) _Float16 h_all[2][16][Hh];   // 8 KB   [team]

    const int tid  = threadIdx.x;
    const int wv8  = tid >> 6;
    const int team = wv8 >> 2;
    const int twv  = wv8 & 3;          // wave-in-team: hdim block (MFMA) / row (LN)
    const int lane = tid & 63;
    const int gq   = lane >> 4;
    const int p16  = lane & 15;
    const int bb   = blockIdx.x;

    // zero h tiles (rows RPT..15 stay zero forever)
    {
        uint* hz = (uint*)h_all;
        #pragma unroll
        for (int i = 0; i < 4; ++i) hz[tid + 512 * i] = 0u;
    }

    // Wh B-fragments, hdim-grouped: tt = g*2+hh -> col = g*128 + twv*32 + hh*16 + p16
    half8 bfrag[8][4];
    #pragma unroll
    for (int g = 0; g < 4; ++g) {
        #pragma unroll
        for (int hh = 0; hh < 2; ++hh) {
            #pragma unroll
            for (int ks = 0; ks < 4; ++ks) {
                half8 h;
                #pragma unroll
                for (int j = 0; j < 8; ++j) {
                    h[j] = (_Float16)W[(size_t)(Ee + ks * 32 + gq * 8 + j) * G4
                                       + g * 128 + twv * 32 + hh * 16 + p16];
                }
                bfrag[g * 2 + hh][ks] = h;
            }
        }
    }

    // LN params: lane owns hdims 2*lane, 2*lane+1 for all gates
    float2 gg[4], sg[4];
    #pragma unroll
    for (int g = 0; g < 4; ++g) {
        gg[g] = *(const float2*)&gains[g * Hh + 2 * lane];
        sg[g] = *(const float2*)&shifts[g * Hh + 2 * lane];
    }
    const float2 gcell = *(const float2*)&gains[4 * Hh + 2 * lane];
    const float2 scell = *(const float2*)&shifts[4 * Hh + 2 * lane];

    const int  row_g = bb * RPBLK + team * RPT + twv;
    const int* xrow  = x + (size_t)row_g * Tt;

    float c0 = 0.f, c1 = 0.f;

    // P prefetch (double-buffered): pc = step 0
    float2 pc[4], pn[4];
    {
        int tok0 = xrow[0];
        #pragma unroll
        for (int g = 0; g < 4; ++g)
            pc[g] = *(const float2*)&P[(size_t)tok0 * G4 + g * 128 + 2 * lane];
        #pragma unroll
        for (int g = 0; g < 4; ++g) pn[g] = pc[g];
    }

    float* const zt = &z5[team][0];
    char*  const hb = (char*)&h_all[team][0][0];

    __syncthreads();

    for (int i = 0; i <= 2 * Tt; ++i) {
        const int  ms   = i >> 1;
        const bool do_m = ((i & 1) == team) && (ms < Tt);
        const int  ls   = (i - 1) >> 1;
        const bool do_l = ((i & 1) != team) && (i >= 1) && (ls < Tt);

        if (do_m) {
            // prefetch P for step ms+1 (consumed 2 intervals later)
            {
                int nst  = (ms + 1 < Tt) ? ms + 1 : Tt - 1;
                int tokn = xrow[nst];
                #pragma unroll
                for (int g = 0; g < 4; ++g)
                    pn[g] = *(const float2*)&P[(size_t)tokn * G4 + g * 128 + 2 * lane];
            }

            // A-fragments from team h tile (swizzled)
            half8 af[4];
            #pragma unroll
            for (int ks = 0; ks < 4; ++ks) {
                af[ks] = *(const half8*)(hb + p16 * 256
                              + ((ks * 64 + (gq << 4)) ^ ((p16 & 7) << 4)));
            }

            f32x4 acc[8];
            #pragma unroll
            for (int tt = 0; tt < 8; ++tt) acc[tt] = (f32x4){0.f, 0.f, 0.f, 0.f};
            #pragma unroll
            for (int tt = 0; tt < 8; ++tt) {
                #pragma unroll
                for (int ks = 0; ks < 4; ++ks) {
                    acc[tt] = __builtin_amdgcn_mfma_f32_16x16x32_f16(
                        af[ks], bfrag[tt][ks], acc[tt], 0, 0, 0);
                }
            }

            // z stage: [col][5] layout, conflict-free (banks 16hh+5p+r)
            if (lane < 16) {
                #pragma unroll
                for (int g = 0; g < 4; ++g) {
                    #pragma unroll
                    for (int hh = 0; hh < 2; ++hh) {
                        const int tt  = g * 2 + hh;
                        const int col = g * 128 + twv * 32 + hh * 16 + p16;
                        float* zp = zt + col * 5;
                        zp[0] = acc[tt][0];
                        zp[1] = acc[tt][1];
                        zp[2] = acc[tt][2];
                        zp[3] = acc[tt][3];
                    }
                }
            }
        }

        if (do_l) {
            const int r = twv;   // team-local row
            // z read (read2: offsets 0,5) + P add; hdims 2*lane, 2*lane+1
            float2 zi[4];
            #pragma unroll
            for (int g = 0; g < 4; ++g) {
                const float* zp = zt + (g * 128 + 2 * lane) * 5 + r;
                zi[g].x = zp[0] + pc[g].x;
                zi[g].y = zp[5] + pc[g].y;
            }

            // gate-LN stats: 8 independent DPP reduction chains
            float mean[4], rstd[4];
            #pragma unroll
            for (int g = 0; g < 4; ++g) {
                float s = red64b(zi[g].x + zi[g].y);
                float q = red64b(fmaf(zi[g].x, zi[g].x, zi[g].y * zi[g].y));
                mean[g] = s * (1.0f / Hh);
                float var = q * (1.0f / Hh) - mean[g] * mean[g];
                rstd[g] = rsqrtf(var + EPS);
            }
            float2 nv[4];
            #pragma unroll
            for (int g = 0; g < 4; ++g) {
                nv[g].x = (zi[g].x - mean[g]) * rstd[g] * gg[g].x + sg[g].x;
                nv[g].y = (zi[g].y - mean[g]) * rstd[g] * gg[g].y + sg[g].y;
            }

            // cell update (gates: 0=i, 1=j, 2=f, 3=o)
            c0 = c0 * sigm(nv[2].x + FBIAS) + sigm(nv[0].x) * fmaxf(nv[1].x, 0.f);
            c1 = c1 * sigm(nv[2].y + FBIAS) + sigm(nv[0].y) * fmaxf(nv[1].y, 0.f);

            // cell-LN over 128 hdims
            float s2 = red64b(c0 + c1);
            float q2 = red64b(fmaf(c0, c0, c1 * c1));
            const float m2 = s2 * (1.0f / Hh);
            const float v2 = q2 * (1.0f / Hh) - m2 * m2;
            const float r2 = rsqrtf(v2 + EPS);
            const float lc0 = (c0 - m2) * r2 * gcell.x + scell.x;
            const float lc1 = (c1 - m2) * r2 * gcell.y + scell.y;
            const float h0 = fmaxf(lc0, 0.f) * sigm(nv[3].x);
            const float h1 = fmaxf(lc1, 0.f) * sigm(nv[3].y);

            // h write (f16, swizzled row r) + output
            {
                union { _Float16 hh2[2]; uint u; } pk;
                pk.hh2[0] = (_Float16)h0; pk.hh2[1] = (_Float16)h1;
                *(uint*)(hb + r * 256 + ((4 * lane) ^ (r << 4))) = pk.u;
            }
            *(float2*)&out[((size_t)row_g * Tt + ls) * Hh + 2 * lane] = (float2){h0, h1};

            #pragma unroll
            for (int g = 0; g < 4; ++g) pc[g] = pn[g];
        }

        lds_barrier();
    }
}

// ---------------------------------------------------------------------------
extern "C" void kernel_launch(void* const* d_in, const int* in_sizes, int n_in,
                              void* d_out, int out_size, void* d_ws, size_t ws_size,
                              hipStream_t stream) {
    const int*   x      = (const int*)d_in[0];
    const float* embed  = (const float*)d_in[1];
    const float* W      = (const float*)d_in[2];
    const float* gains  = (const float*)d_in[3];
    const float* shifts = (const float*)d_in[4];
    float* out = (float*)d_out;

    float* P = (float*)d_ws;   // [V, 4H] = 102.4 MB

    embed_proj_mfma<<<dim3(782), dim3(512), 0, stream>>>(embed, W, P);
    lstm_mfma3<<<dim3(LBLK), dim3(512), 0, stream>>>(P, W, x, gains, shifts, out);
}

// Round 6
// 826.668 us; speedup vs baseline: 1.6353x; 1.6353x over previous
//
#include <hip/hip_runtime.h>
#include <math.h>

// Problem constants (match reference)
#define Bb   256
#define Tt   512
#define Vv   50000
#define Ee   300
#define Hh   128
#define G4   512          // 4*H
#define EPS  1e-12f
#define FBIAS 1.0f

typedef _Float16 half8 __attribute__((ext_vector_type(8)));
typedef float    f32x4 __attribute__((ext_vector_type(4)));

// ---------------------------------------------------------------------------
// Cross-lane helpers (DPP-only reductions)
// ---------------------------------------------------------------------------
template <int CTRL>
__device__ inline float dpp_mov(float v) {
    return __int_as_float(
        __builtin_amdgcn_update_dpp(0, __float_as_int(v), CTRL, 0xF, 0xF, true));
}
// sum over each 16-lane group
__device__ inline float red16(float v) {
    v += dpp_mov<0xB1>(v);    // quad_perm [1,0,3,2]
    v += dpp_mov<0x4E>(v);    // quad_perm [2,3,0,1]
    v += dpp_mov<0x141>(v);   // row_half_mirror
    v += dpp_mov<0x140>(v);   // row_mirror
    return v;
}
// sum over all 64 lanes, broadcast via readlane (pure VALU/DPP, no LDS)
__device__ inline float red64b(float v) {
    v = red16(v);
    v += dpp_mov<0x142>(v);   // row_bcast15
    v += dpp_mov<0x143>(v);   // row_bcast31  => lane63 holds total
    return __int_as_float(__builtin_amdgcn_readlane(__float_as_int(v), 63));
}

// barrier that drains only LDS counters (global prefetches float across)
__device__ inline void lds_barrier() {
    __builtin_amdgcn_sched_barrier(0);
    asm volatile("s_waitcnt lgkmcnt(0)" ::: "memory");
    __builtin_amdgcn_sched_barrier(0);
    __builtin_amdgcn_s_barrier();
    __builtin_amdgcn_sched_barrier(0);
}

__device__ inline float sigm(float v) {
    return __fdividef(1.0f, 1.0f + __expf(-v));
}

// ---------------------------------------------------------------------------
// Phase 1: P[v,:] = embed[v,:] @ W[0:E,:] via f16 MFMA (round-4 config).
// ---------------------------------------------------------------------------
#define PROJ_TILES ((Vv + 31) / 32)

__global__ __launch_bounds__(512, 2) void embed_proj_mfma(
    const float* __restrict__ embed,   // [V, E]
    const float* __restrict__ W,       // [E+H, 4H]
    float* __restrict__ P)             // [V, 4H]
{
    __shared__ __align__(16) _Float16 A[32 * 320];   // 20 KB

    const int tid  = threadIdx.x;
    const int wv   = tid >> 6;
    const int lane = tid & 63;
    const int p16  = lane & 15;
    const int gq   = lane >> 4;

    // B-fragments: col = wv*64 + tt*16 + p16 ; k = ks*32 + gq*8 + j
    half8 bf[4][10];
    #pragma unroll
    for (int tt = 0; tt < 4; ++tt) {
        #pragma unroll
        for (int ks = 0; ks < 10; ++ks) {
            half8 h;
            #pragma unroll
            for (int j = 0; j < 8; ++j) {
                int k = ks * 32 + gq * 8 + j;
                h[j] = (k < Ee)
                     ? (_Float16)W[(size_t)k * G4 + wv * 64 + tt * 16 + p16]
                     : (_Float16)0.f;
            }
            bf[tt][ks] = h;
        }
    }

    char* const Ab = (char*)A;
    for (int i = tid; i < 32 * 10; i += 512) {
        int row = i / 10, m = i - row * 10;
        *(uint*)(Ab + ((row * 640 + 600 + m * 4) ^ ((row & 7) << 4))) = 0u;
    }
    __syncthreads();

    for (int mtile = blockIdx.x; mtile < PROJ_TILES; mtile += gridDim.x) {
        const int r0 = mtile * 32;

        for (int i = tid; i < 32 * 75; i += 512) {
            int row = i / 75, k4 = i - row * 75;
            int grow = r0 + row;
            float4 v = (grow < Vv) ? *(const float4*)&embed[(size_t)grow * Ee + k4 * 4]
                                   : (float4){0.f, 0.f, 0.f, 0.f};
            union { _Float16 h[4]; uint2 u; } pk;
            pk.h[0] = (_Float16)v.x; pk.h[1] = (_Float16)v.y;
            pk.h[2] = (_Float16)v.z; pk.h[3] = (_Float16)v.w;
            *(uint2*)(Ab + ((row * 640 + k4 * 8) ^ ((row & 7) << 4))) = pk.u;
        }
        __syncthreads();

        f32x4 acc[2][4];
        #pragma unroll
        for (int mt = 0; mt < 2; ++mt)
            #pragma unroll
            for (int tt = 0; tt < 4; ++tt)
                acc[mt][tt] = (f32x4){0.f, 0.f, 0.f, 0.f};

        #pragma unroll
        for (int mt = 0; mt < 2; ++mt) {
            const int arow = mt * 16 + p16;
            #pragma unroll
            for (int ks = 0; ks < 10; ++ks) {
                half8 af = *(const half8*)(Ab + ((arow * 640 + ks * 64 + gq * 16)
                                                 ^ ((arow & 7) << 4)));
                #pragma unroll
                for (int tt = 0; tt < 4; ++tt)
                    acc[mt][tt] = __builtin_amdgcn_mfma_f32_16x16x32_f16(
                        af, bf[tt][ks], acc[mt][tt], 0, 0, 0);
            }
        }

        #pragma unroll
        for (int mt = 0; mt < 2; ++mt)
            #pragma unroll
            for (int tt = 0; tt < 4; ++tt)
                #pragma unroll
                for (int r = 0; r < 4; ++r) {
                    int row = r0 + mt * 16 + gq * 4 + r;
                    if (row < Vv)
                        P[(size_t)row * G4 + wv * 64 + tt * 16 + p16] = acc[mt][tt][r];
                }
        __syncthreads();
    }
}

// ---------------------------------------------------------------------------
// Phase 2: 64 blocks x 4 rows x 4 waves (256 thr), 2 lgkm-barriers per step.
//  - B-frags hdim-grouped: wave wv owns hdims wv*32..+31 for ALL 4 gates.
//  - M phase: z = h @ Wh (32 MFMA), z staged row-major [4][512] f32:
//    writes conflict-free (16 lanes, distinct banks), reads b64 2-way (free).
//  - L phase (wave wv = row wv): lane owns hdims 2l,2l+1 of all gates ->
//    no transpose. All reductions pure-DPP (red64b), no LDS hops.
//  - P[x[row,t]] prefetched one step ahead, double-buffered via 2-step unroll.
// ---------------------------------------------------------------------------
#define RPBLK 4
#define LBLK  (Bb / RPBLK)   // 64 blocks

#define LSTM_STEP(TSTEP, PC, PN)                                               \
{                                                                              \
    /* ---- M phase: prefetch P(t+1) + MFMA + z stage ---- */                  \
    {                                                                          \
        int tn   = ((TSTEP) + 1 < Tt) ? (TSTEP) + 1 : Tt - 1;                  \
        int tokn = xrow[tn];                                                   \
        _Pragma("unroll")                                                      \
        for (int g = 0; g < 4; ++g)                                            \
            PN[g] = *(const float2*)&P[(size_t)tokn * G4 + g * 128 + 2 * lane];\
    }                                                                          \
    {                                                                          \
        half8 af[4];                                                           \
        _Pragma("unroll")                                                      \
        for (int ks = 0; ks < 4; ++ks)                                         \
            af[ks] = *(const half8*)(hb + p16 * 256 +                          \
                         ((ks * 64 + (gq << 4)) ^ ((p16 & 7) << 4)));          \
        f32x4 acc[8];                                                          \
        _Pragma("unroll")                                                      \
        for (int tt = 0; tt < 8; ++tt) acc[tt] = (f32x4){0.f, 0.f, 0.f, 0.f};  \
        _Pragma("unroll")                                                      \
        for (int tt = 0; tt < 8; ++tt) {                                       \
            _Pragma("unroll")                                                  \
            for (int ks = 0; ks < 4; ++ks)                                     \
                acc[tt] = __builtin_amdgcn_mfma_f32_16x16x32_f16(              \
                    af[ks], bfrag[tt][ks], acc[tt], 0, 0, 0);                  \
        }                                                                      \
        if (lane < 16) {                                                       \
            _Pragma("unroll")                                                  \
            for (int g = 0; g < 4; ++g) {                                      \
                _Pragma("unroll")                                              \
                for (int hh = 0; hh < 2; ++hh) {                               \
                    const int tt  = g * 2 + hh;                                \
                    const int col = g * 128 + wv * 32 + hh * 16 + p16;         \
                    _Pragma("unroll")                                          \
                    for (int r = 0; r < 4; ++r) z_lds[r][col] = acc[tt][r];    \
                }                                                              \
            }                                                                  \
        }                                                                      \
    }                                                                          \
    lds_barrier();   /* z staged */                                            \
    /* ---- L phase: LN + cell for row wv, hdims 2*lane, 2*lane+1 ---- */      \
    {                                                                          \
        float2 zi[4];                                                          \
        _Pragma("unroll")                                                      \
        for (int g = 0; g < 4; ++g) {                                          \
            float2 zr = *(const float2*)&z_lds[wv][g * 128 + 2 * lane];        \
            zi[g].x = zr.x + PC[g].x;                                          \
            zi[g].y = zr.y + PC[g].y;                                          \
        }                                                                      \
        float mean[4], rstd[4];                                                \
        _Pragma("unroll")                                                      \
        for (int g = 0; g < 4; ++g) {                                          \
            float s = red64b(zi[g].x + zi[g].y);                               \
            float q = red64b(fmaf(zi[g].x, zi[g].x, zi[g].y * zi[g].y));       \
            mean[g] = s * (1.0f / Hh);                                         \
            float var = q * (1.0f / Hh) - mean[g] * mean[g];                   \
            rstd[g] = rsqrtf(var + EPS);                                       \
        }                                                                      \
        float2 nv[4];                                                          \
        _Pragma("unroll")                                                      \
        for (int g = 0; g < 4; ++g) {                                          \
            nv[g].x = (zi[g].x - mean[g]) * rstd[g] * gg[g].x + sg[g].x;       \
            nv[g].y = (zi[g].y - mean[g]) * rstd[g] * gg[g].y + sg[g].y;       \
        }                                                                      \
        c0 = c0 * sigm(nv[2].x + FBIAS) + sigm(nv[0].x) * fmaxf(nv[1].x, 0.f); \
        c1 = c1 * sigm(nv[2].y + FBIAS) + sigm(nv[0].y) * fmaxf(nv[1].y, 0.f); \
        float s2 = red64b(c0 + c1);                                            \
        float q2 = red64b(fmaf(c0, c0, c1 * c1));                              \
        const float m2 = s2 * (1.0f / Hh);                                     \
        const float v2 = q2 * (1.0f / Hh) - m2 * m2;                           \
        const float r2 = rsqrtf(v2 + EPS);                                     \
        const float lc0 = (c0 - m2) * r2 * gcell.x + scell.x;                  \
        const float lc1 = (c1 - m2) * r2 * gcell.y + scell.y;                  \
        const float h0 = fmaxf(lc0, 0.f) * sigm(nv[3].x);                      \
        const float h1 = fmaxf(lc1, 0.f) * sigm(nv[3].y);                      \
        {                                                                      \
            union { _Float16 hh2[2]; uint u; } pk;                             \
            pk.hh2[0] = (_Float16)h0; pk.hh2[1] = (_Float16)h1;                \
            *(uint*)(hb + wv * 256 + ((4 * lane) ^ ((wv & 7) << 4))) = pk.u;   \
        }                                                                      \
        *(float2*)&out[((size_t)row_g * Tt + (TSTEP)) * Hh + 2 * lane] =       \
            (float2){h0, h1};                                                  \
    }                                                                          \
    lds_barrier();   /* h ready */                                             \
}

__global__ __launch_bounds__(256, 1) void lstm_mfma4(
    const float* __restrict__ P,       // [V, 4H]
    const float* __restrict__ W,       // [E+H, 4H]
    const int*   __restrict__ x,       // [B, T]
    const float* __restrict__ gains,   // [5, H]
    const float* __restrict__ shifts,  // [5, H]
    float* __restrict__ out)           // [B, T, H]
{
    __shared__ __align__(16) float    z_lds[RPBLK][G4];   // 8 KB
    __shared__ __align__(16) _Float16 h_lds[16][Hh];      // 4 KB (swizzled)

    const int tid  = threadIdx.x;
    const int wv   = tid >> 6;         // wave id = hdim block (M) / batch row (L)
    const int lane = tid & 63;
    const int gq   = lane >> 4;
    const int p16  = lane & 15;
    const int bb   = blockIdx.x;

    // zero h tile (rows RPBLK..15 never written again; rows 0..3 init state)
    {
        uint* hz = (uint*)h_lds;
        #pragma unroll
        for (int i = 0; i < 4; ++i) hz[tid + 256 * i] = 0u;
    }

    // Wh B-fragments, hdim-grouped: tt=g*2+hh -> col = g*128 + wv*32 + hh*16 + p16
    half8 bfrag[8][4];
    #pragma unroll
    for (int g = 0; g < 4; ++g) {
        #pragma unroll
        for (int hh = 0; hh < 2; ++hh) {
            #pragma unroll
            for (int ks = 0; ks < 4; ++ks) {
                half8 h;
                #pragma unroll
                for (int j = 0; j < 8; ++j) {
                    h[j] = (_Float16)W[(size_t)(Ee + ks * 32 + gq * 8 + j) * G4
                                       + g * 128 + wv * 32 + hh * 16 + p16];
                }
                bfrag[g * 2 + hh][ks] = h;
            }
        }
    }

    // LN params: lane owns hdims 2*lane, 2*lane+1 for all gates
    float2 gg[4], sg[4];
    #pragma unroll
    for (int g = 0; g < 4; ++g) {
        gg[g] = *(const float2*)&gains[g * Hh + 2 * lane];
        sg[g] = *(const float2*)&shifts[g * Hh + 2 * lane];
    }
    const float2 gcell = *(const float2*)&gains[4 * Hh + 2 * lane];
    const float2 scell = *(const float2*)&shifts[4 * Hh + 2 * lane];

    const int  row_g = bb * RPBLK + wv;
    const int* xrow  = x + (size_t)row_g * Tt;

    float c0 = 0.f, c1 = 0.f;

    // P prefetch prologue (step 0)
    float2 pA[4], pB[4];
    {
        int tok0 = xrow[0];
        #pragma unroll
        for (int g = 0; g < 4; ++g)
            pA[g] = *(const float2*)&P[(size_t)tok0 * G4 + g * 128 + 2 * lane];
    }

    char* const hb = (char*)h_lds;

    __syncthreads();

    for (int t = 0; t < Tt; t += 2) {
        LSTM_STEP(t,     pA, pB)
        LSTM_STEP(t + 1, pB, pA)
    }
}

// ---------------------------------------------------------------------------
extern "C" void kernel_launch(void* const* d_in, const int* in_sizes, int n_in,
                              void* d_out, int out_size, void* d_ws, size_t ws_size,
                              hipStream_t stream) {
    const int*   x      = (const int*)d_in[0];
    const float* embed  = (const float*)d_in[1];
    const float* W      = (const float*)d_in[2];
    const float* gains  = (const float*)d_in[3];
    const float* shifts = (const float*)d_in[4];
    float* out = (float*)d_out;

    float* P = (float*)d_ws;   // [V, 4H] = 102.4 MB

    embed_proj_mfma<<<dim3(256), dim3(512), 0, stream>>>(embed, W, P);
    lstm_mfma4<<<dim3(LBLK), dim3(256), 0, stream>>>(P, W, x, gains, shifts, out);
}

// Round 7
// 794.159 us; speedup vs baseline: 1.7023x; 1.0409x over previous
//
#include <hip/hip_runtime.h>
#include <math.h>

// Problem constants (match reference)
#define Bb   256
#define Tt   512
#define Vv   50000
#define Ee   300
#define Hh   128
#define G4   512          // 4*H
#define EPS  1e-12f
#define FBIAS 1.0f

typedef _Float16 half8 __attribute__((ext_vector_type(8)));
typedef float    f32x4 __attribute__((ext_vector_type(4)));

// ---------------------------------------------------------------------------
// Cross-lane helpers (DPP-only reductions)
// ---------------------------------------------------------------------------
template <int CTRL>
__device__ inline float dpp_mov(float v) {
    return __int_as_float(
        __builtin_amdgcn_update_dpp(0, __float_as_int(v), CTRL, 0xF, 0xF, true));
}
// sum over each 16-lane group
__device__ inline float red16(float v) {
    v += dpp_mov<0xB1>(v);    // quad_perm [1,0,3,2]
    v += dpp_mov<0x4E>(v);    // quad_perm [2,3,0,1]
    v += dpp_mov<0x141>(v);   // row_half_mirror
    v += dpp_mov<0x140>(v);   // row_mirror
    return v;
}
// sum over all 64 lanes, broadcast via readlane (pure VALU/DPP, no LDS)
__device__ inline float red64b(float v) {
    v = red16(v);
    v += dpp_mov<0x142>(v);   // row_bcast15
    v += dpp_mov<0x143>(v);   // row_bcast31  => lane63 holds total
    return __int_as_float(__builtin_amdgcn_readlane(__float_as_int(v), 63));
}

// barrier that drains only LDS counters (global prefetches float across)
__device__ inline void lds_barrier() {
    __builtin_amdgcn_sched_barrier(0);
    asm volatile("s_waitcnt lgkmcnt(0)" ::: "memory");
    __builtin_amdgcn_sched_barrier(0);
    __builtin_amdgcn_s_barrier();
    __builtin_amdgcn_sched_barrier(0);
}

__device__ inline float sigm(float v) {
    return __fdividef(1.0f, 1.0f + __expf(-v));
}

// ---------------------------------------------------------------------------
// Phase 1: P[v,:] = embed[v,:] @ W[0:E,:] via f16 MFMA. P stored f16.
// ---------------------------------------------------------------------------
#define PROJ_TILES ((Vv + 31) / 32)

__global__ __launch_bounds__(512, 2) void embed_proj_mfma(
    const float* __restrict__ embed,   // [V, E]
    const float* __restrict__ W,       // [E+H, 4H]
    _Float16* __restrict__ P)          // [V, 4H] f16
{
    __shared__ __align__(16) _Float16 A[32 * 320];   // 20 KB

    const int tid  = threadIdx.x;
    const int wv   = tid >> 6;
    const int lane = tid & 63;
    const int p16  = lane & 15;
    const int gq   = lane >> 4;

    // B-fragments: col = wv*64 + tt*16 + p16 ; k = ks*32 + gq*8 + j
    half8 bf[4][10];
    #pragma unroll
    for (int tt = 0; tt < 4; ++tt) {
        #pragma unroll
        for (int ks = 0; ks < 10; ++ks) {
            half8 h;
            #pragma unroll
            for (int j = 0; j < 8; ++j) {
                int k = ks * 32 + gq * 8 + j;
                h[j] = (k < Ee)
                     ? (_Float16)W[(size_t)k * G4 + wv * 64 + tt * 16 + p16]
                     : (_Float16)0.f;
            }
            bf[tt][ks] = h;
        }
    }

    char* const Ab = (char*)A;
    for (int i = tid; i < 32 * 10; i += 512) {
        int row = i / 10, m = i - row * 10;
        *(uint*)(Ab + ((row * 640 + 600 + m * 4) ^ ((row & 7) << 4))) = 0u;
    }
    __syncthreads();

    for (int mtile = blockIdx.x; mtile < PROJ_TILES; mtile += gridDim.x) {
        const int r0 = mtile * 32;

        for (int i = tid; i < 32 * 75; i += 512) {
            int row = i / 75, k4 = i - row * 75;
            int grow = r0 + row;
            float4 v = (grow < Vv) ? *(const float4*)&embed[(size_t)grow * Ee + k4 * 4]
                                   : (float4){0.f, 0.f, 0.f, 0.f};
            union { _Float16 h[4]; uint2 u; } pk;
            pk.h[0] = (_Float16)v.x; pk.h[1] = (_Float16)v.y;
            pk.h[2] = (_Float16)v.z; pk.h[3] = (_Float16)v.w;
            *(uint2*)(Ab + ((row * 640 + k4 * 8) ^ ((row & 7) << 4))) = pk.u;
        }
        __syncthreads();

        f32x4 acc[2][4];
        #pragma unroll
        for (int mt = 0; mt < 2; ++mt)
            #pragma unroll
            for (int tt = 0; tt < 4; ++tt)
                acc[mt][tt] = (f32x4){0.f, 0.f, 0.f, 0.f};

        #pragma unroll
        for (int mt = 0; mt < 2; ++mt) {
            const int arow = mt * 16 + p16;
            #pragma unroll
            for (int ks = 0; ks < 10; ++ks) {
                half8 af = *(const half8*)(Ab + ((arow * 640 + ks * 64 + gq * 16)
                                                 ^ ((arow & 7) << 4)));
                #pragma unroll
                for (int tt = 0; tt < 4; ++tt)
                    acc[mt][tt] = __builtin_amdgcn_mfma_f32_16x16x32_f16(
                        af, bf[tt][ks], acc[mt][tt], 0, 0, 0);
            }
        }

        #pragma unroll
        for (int mt = 0; mt < 2; ++mt)
            #pragma unroll
            for (int tt = 0; tt < 4; ++tt)
                #pragma unroll
                for (int r = 0; r < 4; ++r) {
                    int row = r0 + mt * 16 + gq * 4 + r;
                    if (row < Vv)
                        P[(size_t)row * G4 + wv * 64 + tt * 16 + p16] =
                            (_Float16)acc[mt][tt][r];
                }
        __syncthreads();
    }
}

// ---------------------------------------------------------------------------
// Phase 2: 64 blocks x 4 rows x 4 waves (256 thr), 2 lgkm-barriers per step.
// Round-6 structure + latency fixes:
//  - tokens staged once in LDS (xtok); next-next token read during prior L
//  - P gather: f16, prefetch depth 2 (pA/pB/pC rotation, 3-step unroll) ->
//    loads retire ~2 full steps before consumption, no vmcnt stall
// ---------------------------------------------------------------------------
#define RPBLK 4
#define LBLK  (Bb / RPBLK)   // 64 blocks

#define LSTM_STEP(TSTEP, PC, PL)                                               \
{                                                                              \
    /* ---- M phase: issue P prefetch for TSTEP+2 (token tkR) ---- */          \
    {                                                                          \
        const _Float16* pr = P + (size_t)tkR * G4;                             \
        _Pragma("unroll")                                                      \
        for (int g = 0; g < 4; ++g)                                            \
            PL[g] = *(const uint*)&pr[g * 128 + 2 * lane];                     \
    }                                                                          \
    {                                                                          \
        half8 af[4];                                                           \
        _Pragma("unroll")                                                      \
        for (int ks = 0; ks < 4; ++ks)                                         \
            af[ks] = *(const half8*)(hb + p16 * 256 +                          \
                         ((ks * 64 + (gq << 4)) ^ ((p16 & 7) << 4)));          \
        f32x4 acc[8];                                                          \
        _Pragma("unroll")                                                      \
        for (int tt = 0; tt < 8; ++tt) acc[tt] = (f32x4){0.f, 0.f, 0.f, 0.f};  \
        _Pragma("unroll")                                                      \
        for (int tt = 0; tt < 8; ++tt) {                                       \
            _Pragma("unroll")                                                  \
            for (int ks = 0; ks < 4; ++ks)                                     \
                acc[tt] = __builtin_amdgcn_mfma_f32_16x16x32_f16(              \
                    af[ks], bfrag[tt][ks], acc[tt], 0, 0, 0);                  \
        }                                                                      \
        if (lane < 16) {                                                       \
            _Pragma("unroll")                                                  \
            for (int g = 0; g < 4; ++g) {                                      \
                _Pragma("unroll")                                              \
                for (int hh = 0; hh < 2; ++hh) {                               \
                    const int tt  = g * 2 + hh;                                \
                    const int col = g * 128 + wv * 32 + hh * 16 + p16;         \
                    _Pragma("unroll")                                          \
                    for (int r = 0; r < 4; ++r) z_lds[r][col] = acc[tt][r];    \
                }                                                              \
            }                                                                  \
        }                                                                      \
    }                                                                          \
    lds_barrier();   /* z staged */                                            \
    /* ---- L phase: LN + cell for row wv, hdims 2*lane, 2*lane+1 ---- */      \
    {                                                                          \
        tkR = xtok[wv][((TSTEP) + 3 < Tt) ? (TSTEP) + 3 : Tt - 1];             \
        float2 zi[4];                                                          \
        _Pragma("unroll")                                                      \
        for (int g = 0; g < 4; ++g) {                                          \
            union { uint u; _Float16 h[2]; } pk; pk.u = PC[g];                 \
            float2 zr = *(const float2*)&z_lds[wv][g * 128 + 2 * lane];        \
            zi[g].x = zr.x + (float)pk.h[0];                                   \
            zi[g].y = zr.y + (float)pk.h[1];                                   \
        }                                                                      \
        float mean[4], rstd[4];                                                \
        _Pragma("unroll")                                                      \
        for (int g = 0; g < 4; ++g) {                                          \
            float s = red64b(zi[g].x + zi[g].y);                               \
            float q = red64b(fmaf(zi[g].x, zi[g].x, zi[g].y * zi[g].y));       \
            mean[g] = s * (1.0f / Hh);                                         \
            float var = q * (1.0f / Hh) - mean[g] * mean[g];                   \
            rstd[g] = rsqrtf(var + EPS);                                       \
        }                                                                      \
        float2 nv[4];                                                          \
        _Pragma("unroll")                                                      \
        for (int g = 0; g < 4; ++g) {                                          \
            nv[g].x = (zi[g].x - mean[g]) * rstd[g] * gg[g].x + sg[g].x;       \
            nv[g].y = (zi[g].y - mean[g]) * rstd[g] * gg[g].y + sg[g].y;       \
        }                                                                      \
        c0 = c0 * sigm(nv[2].x + FBIAS) + sigm(nv[0].x) * fmaxf(nv[1].x, 0.f); \
        c1 = c1 * sigm(nv[2].y + FBIAS) + sigm(nv[0].y) * fmaxf(nv[1].y, 0.f); \
        float s2 = red64b(c0 + c1);                                            \
        float q2 = red64b(fmaf(c0, c0, c1 * c1));                              \
        const float m2 = s2 * (1.0f / Hh);                                     \
        const float v2 = q2 * (1.0f / Hh) - m2 * m2;                           \
        const float r2 = rsqrtf(v2 + EPS);                                     \
        const float lc0 = (c0 - m2) * r2 * gcell.x + scell.x;                  \
        const float lc1 = (c1 - m2) * r2 * gcell.y + scell.y;                  \
        const float h0 = fmaxf(lc0, 0.f) * sigm(nv[3].x);                      \
        const float h1 = fmaxf(lc1, 0.f) * sigm(nv[3].y);                      \
        {                                                                      \
            union { _Float16 hh2[2]; uint u; } pk;                             \
            pk.hh2[0] = (_Float16)h0; pk.hh2[1] = (_Float16)h1;                \
            *(uint*)(hb + wv * 256 + ((4 * lane) ^ ((wv & 7) << 4))) = pk.u;   \
        }                                                                      \
        *(float2*)&out[((size_t)row_g * Tt + (TSTEP)) * Hh + 2 * lane] =       \
            (float2){h0, h1};                                                  \
    }                                                                          \
    lds_barrier();   /* h ready */                                             \
}

__global__ __launch_bounds__(256, 1) void lstm_mfma5(
    const _Float16* __restrict__ P,    // [V, 4H] f16
    const float* __restrict__ W,       // [E+H, 4H]
    const int*   __restrict__ x,       // [B, T]
    const float* __restrict__ gains,   // [5, H]
    const float* __restrict__ shifts,  // [5, H]
    float* __restrict__ out)           // [B, T, H]
{
    __shared__ __align__(16) float    z_lds[RPBLK][G4];   // 8 KB
    __shared__ __align__(16) _Float16 h_lds[16][Hh];      // 4 KB (swizzled)
    __shared__ __align__(16) int      xtok[RPBLK][Tt];    // 8 KB

    const int tid  = threadIdx.x;
    const int wv   = tid >> 6;         // wave id = hdim block (M) / batch row (L)
    const int lane = tid & 63;
    const int gq   = lane >> 4;
    const int p16  = lane & 15;
    const int bb   = blockIdx.x;

    // stage tokens for this block's 4 rows (contiguous 8 KB)
    {
        const int4* xs = (const int4*)(x + (size_t)bb * RPBLK * Tt);
        int4* xd = (int4*)&xtok[0][0];
        for (int i = tid; i < 512; i += 256) xd[i] = xs[i];
    }

    // zero h tile (rows RPBLK..15 never written again; rows 0..3 init state)
    {
        uint* hz = (uint*)h_lds;
        #pragma unroll
        for (int i = 0; i < 4; ++i) hz[tid + 256 * i] = 0u;
    }

    // Wh B-fragments, hdim-grouped: tt=g*2+hh -> col = g*128 + wv*32 + hh*16 + p16
    half8 bfrag[8][4];
    #pragma unroll
    for (int g = 0; g < 4; ++g) {
        #pragma unroll
        for (int hh = 0; hh < 2; ++hh) {
            #pragma unroll
            for (int ks = 0; ks < 4; ++ks) {
                half8 h;
                #pragma unroll
                for (int j = 0; j < 8; ++j) {
                    h[j] = (_Float16)W[(size_t)(Ee + ks * 32 + gq * 8 + j) * G4
                                       + g * 128 + wv * 32 + hh * 16 + p16];
                }
                bfrag[g * 2 + hh][ks] = h;
            }
        }
    }

    // LN params: lane owns hdims 2*lane, 2*lane+1 for all gates
    float2 gg[4], sg[4];
    #pragma unroll
    for (int g = 0; g < 4; ++g) {
        gg[g] = *(const float2*)&gains[g * Hh + 2 * lane];
        sg[g] = *(const float2*)&shifts[g * Hh + 2 * lane];
    }
    const float2 gcell = *(const float2*)&gains[4 * Hh + 2 * lane];
    const float2 scell = *(const float2*)&shifts[4 * Hh + 2 * lane];

    const int row_g = bb * RPBLK + wv;

    float c0 = 0.f, c1 = 0.f;
    char* const hb = (char*)h_lds;

    __syncthreads();   // tokens + h staged

    // P prefetch prologue: steps 0 and 1; tkR = token for step 2
    uint pA[4], pB[4], pC[4];
    int tkR;
    {
        int tk0 = xtok[wv][0];
        int tk1 = xtok[wv][1];
        tkR = xtok[wv][2];
        const _Float16* p0 = P + (size_t)tk0 * G4;
        const _Float16* p1 = P + (size_t)tk1 * G4;
        #pragma unroll
        for (int g = 0; g < 4; ++g) {
            pA[g] = *(const uint*)&p0[g * 128 + 2 * lane];
            pB[g] = *(const uint*)&p1[g * 128 + 2 * lane];
        }
    }

    for (int t = 0; t < 510; t += 3) {
        LSTM_STEP(t,     pA, pC)
        LSTM_STEP(t + 1, pB, pA)
        LSTM_STEP(t + 2, pC, pB)
    }
    LSTM_STEP(510, pA, pC)
    LSTM_STEP(511, pB, pA)
}

// ---------------------------------------------------------------------------
extern "C" void kernel_launch(void* const* d_in, const int* in_sizes, int n_in,
                              void* d_out, int out_size, void* d_ws, size_t ws_size,
                              hipStream_t stream) {
    const int*   x      = (const int*)d_in[0];
    const float* embed  = (const float*)d_in[1];
    const float* W      = (const float*)d_in[2];
    const float* gains  = (const float*)d_in[3];
    const float* shifts = (const float*)d_in[4];
    float* out = (float*)d_out;

    _Float16* P = (_Float16*)d_ws;   // [V, 4H] f16 = 51.2 MB

    embed_proj_mfma<<<dim3(256), dim3(512), 0, stream>>>(embed, W, P);
    lstm_mfma5<<<dim3(LBLK), dim3(256), 0, stream>>>(P, W, x, gains, shifts, out);
}

// Round 8
// 788.576 us; speedup vs baseline: 1.7143x; 1.0071x over previous
//
#include <hip/hip_runtime.h>
#include <math.h>

// Problem constants (match reference)
#define Bb   256
#define Tt   512
#define Vv   50000
#define Ee   300
#define Hh   128
#define G4   512          // 4*H
#define EPS  1e-12f
#define FBIAS 1.0f

typedef _Float16 half8 __attribute__((ext_vector_type(8)));
typedef float    f32x4 __attribute__((ext_vector_type(4)));

// ---------------------------------------------------------------------------
// Cross-lane helpers (DPP-only reductions)
// ---------------------------------------------------------------------------
template <int CTRL>
__device__ inline float dpp_mov(float v) {
    return __int_as_float(
        __builtin_amdgcn_update_dpp(0, __float_as_int(v), CTRL, 0xF, 0xF, true));
}
__device__ inline float red16(float v) {
    v += dpp_mov<0xB1>(v);    // quad_perm [1,0,3,2]
    v += dpp_mov<0x4E>(v);    // quad_perm [2,3,0,1]
    v += dpp_mov<0x141>(v);   // row_half_mirror
    v += dpp_mov<0x140>(v);   // row_mirror
    return v;
}
__device__ inline float red64b(float v) {
    v = red16(v);
    v += dpp_mov<0x142>(v);   // row_bcast15
    v += dpp_mov<0x143>(v);   // row_bcast31  => lane63 holds total
    return __int_as_float(__builtin_amdgcn_readlane(__float_as_int(v), 63));
}

// LDS-only barrier: drain lgkmcnt, raw s_barrier (vm prefetches float across)
__device__ inline void lds_barrier() {
    asm volatile("s_waitcnt lgkmcnt(0)" ::: "memory");
    __builtin_amdgcn_s_barrier();
}

__device__ inline float sigm(float v) {
    return __fdividef(1.0f, 1.0f + __expf(-v));
}

// ---------------------------------------------------------------------------
// Phase 1: P[v,:] = embed[v,:] @ W[0:E,:] via f16 MFMA. P stored f16.
// ---------------------------------------------------------------------------
#define PROJ_TILES ((Vv + 31) / 32)

__global__ __launch_bounds__(512, 2) void embed_proj_mfma(
    const float* __restrict__ embed,   // [V, E]
    const float* __restrict__ W,       // [E+H, 4H]
    _Float16* __restrict__ P)          // [V, 4H] f16
{
    __shared__ __align__(16) _Float16 A[32 * 320];   // 20 KB

    const int tid  = threadIdx.x;
    const int wv   = tid >> 6;
    const int lane = tid & 63;
    const int p16  = lane & 15;
    const int gq   = lane >> 4;

    half8 bf[4][10];
    #pragma unroll
    for (int tt = 0; tt < 4; ++tt) {
        #pragma unroll
        for (int ks = 0; ks < 10; ++ks) {
            half8 h;
            #pragma unroll
            for (int j = 0; j < 8; ++j) {
                int k = ks * 32 + gq * 8 + j;
                h[j] = (k < Ee)
                     ? (_Float16)W[(size_t)k * G4 + wv * 64 + tt * 16 + p16]
                     : (_Float16)0.f;
            }
            bf[tt][ks] = h;
        }
    }

    char* const Ab = (char*)A;
    for (int i = tid; i < 32 * 10; i += 512) {
        int row = i / 10, m = i - row * 10;
        *(uint*)(Ab + ((row * 640 + 600 + m * 4) ^ ((row & 7) << 4))) = 0u;
    }
    __syncthreads();

    for (int mtile = blockIdx.x; mtile < PROJ_TILES; mtile += gridDim.x) {
        const int r0 = mtile * 32;

        for (int i = tid; i < 32 * 75; i += 512) {
            int row = i / 75, k4 = i - row * 75;
            int grow = r0 + row;
            float4 v = (grow < Vv) ? *(const float4*)&embed[(size_t)grow * Ee + k4 * 4]
                                   : (float4){0.f, 0.f, 0.f, 0.f};
            union { _Float16 h[4]; uint2 u; } pk;
            pk.h[0] = (_Float16)v.x; pk.h[1] = (_Float16)v.y;
            pk.h[2] = (_Float16)v.z; pk.h[3] = (_Float16)v.w;
            *(uint2*)(Ab + ((row * 640 + k4 * 8) ^ ((row & 7) << 4))) = pk.u;
        }
        __syncthreads();

        f32x4 acc[2][4];
        #pragma unroll
        for (int mt = 0; mt < 2; ++mt)
            #pragma unroll
            for (int tt = 0; tt < 4; ++tt)
                acc[mt][tt] = (f32x4){0.f, 0.f, 0.f, 0.f};

        #pragma unroll
        for (int mt = 0; mt < 2; ++mt) {
            const int arow = mt * 16 + p16;
            #pragma unroll
            for (int ks = 0; ks < 10; ++ks) {
                half8 af = *(const half8*)(Ab + ((arow * 640 + ks * 64 + gq * 16)
                                                 ^ ((arow & 7) << 4)));
                #pragma unroll
                for (int tt = 0; tt < 4; ++tt)
                    acc[mt][tt] = __builtin_amdgcn_mfma_f32_16x16x32_f16(
                        af, bf[tt][ks], acc[mt][tt], 0, 0, 0);
            }
        }

        #pragma unroll
        for (int mt = 0; mt < 2; ++mt)
            #pragma unroll
            for (int tt = 0; tt < 4; ++tt)
                #pragma unroll
                for (int r = 0; r < 4; ++r) {
                    int row = r0 + mt * 16 + gq * 4 + r;
                    if (row < Vv)
                        P[(size_t)row * G4 + wv * 64 + tt * 16 + p16] =
                            (_Float16)acc[mt][tt][r];
                }
        __syncthreads();
    }
}

// ---------------------------------------------------------------------------
// Wsum[k][g] = sum over gate g's 128 cols of W[Ee+k][*]   (128 x 4 f32)
// ---------------------------------------------------------------------------
__global__ __launch_bounds__(128) void wsum_kernel(
    const float* __restrict__ W, float* __restrict__ Wsum)
{
    const int k = threadIdx.x;          // 0..127
    const float* wr = W + (size_t)(Ee + k) * G4;
    #pragma unroll
    for (int g = 0; g < 4; ++g) {
        float s = 0.f;
        for (int c = 0; c < 128; c += 4) {
            float4 v = *(const float4*)&wr[g * 128 + c];
            s += (v.x + v.y) + (v.z + v.w);
        }
        Wsum[k * 4 + g] = s;
    }
}

// ---------------------------------------------------------------------------
// P_sum[v][g] = sum over gate g's 128 cols of P[v][*]   (V x 4 f32)
// one wave per row, grid-stride
// ---------------------------------------------------------------------------
__global__ __launch_bounds__(256) void psum_kernel(
    const _Float16* __restrict__ P, float* __restrict__ Psum)
{
    const int lane = threadIdx.x & 63;
    const int wid  = (blockIdx.x * 256 + threadIdx.x) >> 6;
    const int nw   = (gridDim.x * 256) >> 6;
    const int g    = lane >> 4;

    for (int row = wid; row < Vv; row += nw) {
        half8 v = *(const half8*)&P[(size_t)row * G4 + lane * 8];
        float s = 0.f;
        #pragma unroll
        for (int j = 0; j < 8; ++j) s += (float)v[j];
        s = red16(s);                          // per-16-lane group = per gate
        if ((lane & 15) == 0) Psum[row * 4 + g] = s;
    }
}

// ---------------------------------------------------------------------------
// Phase 2: 64 blocks x 4 rows x 4 waves, 2 lgkm-barriers per step.
// Round-7 structure +:
//  - gate means via Wsum MFMA (acc_s) + P_sum table: only q needs red64b
//  - P/P_sum prefetch depth 3 (4 rotating buffers)
//  - no sched_barriers (compiler may fill stall slots)
// ---------------------------------------------------------------------------
#define RPBLK 4
#define LBLK  (Bb / RPBLK)   // 64 blocks

#define LSTM_STEP(TSTEP, PC, QC, PL, QL)                                       \
{                                                                              \
    /* ---- M phase: issue P prefetch for TSTEP+3 (token tkR) ---- */          \
    {                                                                          \
        const _Float16* pr = P + (size_t)tkR * G4;                             \
        _Pragma("unroll")                                                      \
        for (int g = 0; g < 4; ++g)                                            \
            PL[g] = *(const uint*)&pr[g * 128 + 2 * lane];                     \
        QL = *(const float4*)&Psum[(size_t)tkR * 4];                           \
    }                                                                          \
    f32x4 acc_s = (f32x4){0.f, 0.f, 0.f, 0.f};                                 \
    {                                                                          \
        half8 af[4];                                                           \
        _Pragma("unroll")                                                      \
        for (int ks = 0; ks < 4; ++ks)                                         \
            af[ks] = *(const half8*)(hb + p16 * 256 +                          \
                         ((ks * 64 + (gq << 4)) ^ ((p16 & 7) << 4)));          \
        f32x4 acc[8];                                                          \
        _Pragma("unroll")                                                      \
        for (int tt = 0; tt < 8; ++tt) acc[tt] = (f32x4){0.f, 0.f, 0.f, 0.f};  \
        _Pragma("unroll")                                                      \
        for (int tt = 0; tt < 8; ++tt) {                                       \
            _Pragma("unroll")                                                  \
            for (int ks = 0; ks < 4; ++ks)                                     \
                acc[tt] = __builtin_amdgcn_mfma_f32_16x16x32_f16(              \
                    af[ks], bfrag[tt][ks], acc[tt], 0, 0, 0);                  \
        }                                                                      \
        _Pragma("unroll")                                                      \
        for (int ks = 0; ks < 4; ++ks)                                         \
            acc_s = __builtin_amdgcn_mfma_f32_16x16x32_f16(                    \
                af[ks], bsum[ks], acc_s, 0, 0, 0);                             \
        if (lane < 16) {                                                       \
            _Pragma("unroll")                                                  \
            for (int g = 0; g < 4; ++g) {                                      \
                _Pragma("unroll")                                              \
                for (int hh = 0; hh < 2; ++hh) {                               \
                    const int tt  = g * 2 + hh;                                \
                    const int col = g * 128 + wv * 32 + hh * 16 + p16;         \
                    _Pragma("unroll")                                          \
                    for (int r = 0; r < 4; ++r) z_lds[r][col] = acc[tt][r];    \
                }                                                              \
            }                                                                  \
        }                                                                      \
    }                                                                          \
    lds_barrier();   /* z staged */                                            \
    /* ---- L phase: LN + cell for row wv, hdims 2*lane, 2*lane+1 ---- */      \
    {                                                                          \
        tkR = xtok[wv][((TSTEP) + 4 < Tt) ? (TSTEP) + 4 : Tt - 1];             \
        float2 zi[4];                                                          \
        _Pragma("unroll")                                                      \
        for (int g = 0; g < 4; ++g) {                                          \
            union { uint u; _Float16 h[2]; } pk; pk.u = PC[g];                 \
            float2 zr = *(const float2*)&z_lds[wv][g * 128 + 2 * lane];        \
            zi[g].x = zr.x + (float)pk.h[0];                                   \
            zi[g].y = zr.y + (float)pk.h[1];                                   \
        }                                                                      \
        /* means: row-sum via acc_s (this wave's row = reg wv) + P_sum */      \
        float sr = acc_s[0];                                                   \
        sr = (wv == 1) ? acc_s[1] : sr;                                        \
        sr = (wv == 2) ? acc_s[2] : sr;                                        \
        sr = (wv == 3) ? acc_s[3] : sr;                                        \
        float mean[4], rstd[4];                                                \
        {                                                                      \
            const float qs[4] = {QC.x, QC.y, QC.z, QC.w};                      \
            _Pragma("unroll")                                                  \
            for (int g = 0; g < 4; ++g) {                                      \
                float sg_ = __int_as_float(                                    \
                    __builtin_amdgcn_readlane(__float_as_int(sr), g));         \
                mean[g] = (qs[g] + sg_) * (1.0f / Hh);                         \
            }                                                                  \
        }                                                                      \
        _Pragma("unroll")                                                      \
        for (int g = 0; g < 4; ++g) {                                          \
            float q = red64b(fmaf(zi[g].x, zi[g].x, zi[g].y * zi[g].y));       \
            float var = q * (1.0f / Hh) - mean[g] * mean[g];                   \
            rstd[g] = rsqrtf(var + EPS);                                       \
        }                                                                      \
        float2 nv[4];                                                          \
        _Pragma("unroll")                                                      \
        for (int g = 0; g < 4; ++g) {                                          \
            nv[g].x = (zi[g].x - mean[g]) * rstd[g] * gg[g].x + sg[g].x;       \
            nv[g].y = (zi[g].y - mean[g]) * rstd[g] * gg[g].y + sg[g].y;       \
        }                                                                      \
        const float sox = sigm(nv[3].x);  /* off critical path */              \
        const float soy = sigm(nv[3].y);                                       \
        c0 = c0 * sigm(nv[2].x + FBIAS) + sigm(nv[0].x) * fmaxf(nv[1].x, 0.f); \
        c1 = c1 * sigm(nv[2].y + FBIAS) + sigm(nv[0].y) * fmaxf(nv[1].y, 0.f); \
        float s2 = red64b(c0 + c1);                                            \
        float q2 = red64b(fmaf(c0, c0, c1 * c1));                              \
        const float m2 = s2 * (1.0f / Hh);                                     \
        const float v2 = q2 * (1.0f / Hh) - m2 * m2;                           \
        const float r2 = rsqrtf(v2 + EPS);                                     \
        const float lc0 = (c0 - m2) * r2 * gcell.x + scell.x;                  \
        const float lc1 = (c1 - m2) * r2 * gcell.y + scell.y;                  \
        const float h0 = fmaxf(lc0, 0.f) * sox;                                \
        const float h1 = fmaxf(lc1, 0.f) * soy;                                \
        {                                                                      \
            union { _Float16 hh2[2]; uint u; } pk;                             \
            pk.hh2[0] = (_Float16)h0; pk.hh2[1] = (_Float16)h1;                \
            *(uint*)(hb + wv * 256 + ((4 * lane) ^ ((wv & 7) << 4))) = pk.u;   \
        }                                                                      \
        *(float2*)&out[((size_t)row_g * Tt + (TSTEP)) * Hh + 2 * lane] =       \
            (float2){h0, h1};                                                  \
    }                                                                          \
    lds_barrier();   /* h ready */                                             \
}

__global__ __launch_bounds__(256, 1) void lstm_mfma6(
    const _Float16* __restrict__ P,    // [V, 4H] f16
    const float* __restrict__ Psum,    // [V, 4] f32
    const float* __restrict__ Wsum,    // [128, 4] f32
    const float* __restrict__ W,       // [E+H, 4H]
    const int*   __restrict__ x,       // [B, T]
    const float* __restrict__ gains,   // [5, H]
    const float* __restrict__ shifts,  // [5, H]
    float* __restrict__ out)           // [B, T, H]
{
    __shared__ __align__(16) float    z_lds[RPBLK][G4];   // 8 KB
    __shared__ __align__(16) _Float16 h_lds[16][Hh];      // 4 KB (swizzled)
    __shared__ __align__(16) int      xtok[RPBLK][Tt];    // 8 KB

    const int tid  = threadIdx.x;
    const int wv   = tid >> 6;
    const int lane = tid & 63;
    const int gq   = lane >> 4;
    const int p16  = lane & 15;
    const int bb   = blockIdx.x;

    // stage tokens for this block's 4 rows
    {
        const int4* xs = (const int4*)(x + (size_t)bb * RPBLK * Tt);
        int4* xd = (int4*)&xtok[0][0];
        for (int i = tid; i < 512; i += 256) xd[i] = xs[i];
    }

    // zero h tile
    {
        uint* hz = (uint*)h_lds;
        #pragma unroll
        for (int i = 0; i < 4; ++i) hz[tid + 256 * i] = 0u;
    }

    // Wh B-fragments, hdim-grouped
    half8 bfrag[8][4];
    #pragma unroll
    for (int g = 0; g < 4; ++g) {
        #pragma unroll
        for (int hh = 0; hh < 2; ++hh) {
            #pragma unroll
            for (int ks = 0; ks < 4; ++ks) {
                half8 h;
                #pragma unroll
                for (int j = 0; j < 8; ++j) {
                    h[j] = (_Float16)W[(size_t)(Ee + ks * 32 + gq * 8 + j) * G4
                                       + g * 128 + wv * 32 + hh * 16 + p16];
                }
                bfrag[g * 2 + hh][ks] = h;
            }
        }
    }

    // Wsum B-fragment: col c holds Wsum[:, c&3]
    half8 bsum[4];
    #pragma unroll
    for (int ks = 0; ks < 4; ++ks) {
        half8 h;
        #pragma unroll
        for (int j = 0; j < 8; ++j)
            h[j] = (_Float16)Wsum[(ks * 32 + gq * 8 + j) * 4 + (p16 & 3)];
        bsum[ks] = h;
    }

    // LN params
    float2 gg[4], sg[4];
    #pragma unroll
    for (int g = 0; g < 4; ++g) {
        gg[g] = *(const float2*)&gains[g * Hh + 2 * lane];
        sg[g] = *(const float2*)&shifts[g * Hh + 2 * lane];
    }
    const float2 gcell = *(const float2*)&gains[4 * Hh + 2 * lane];
    const float2 scell = *(const float2*)&shifts[4 * Hh + 2 * lane];

    const int row_g = bb * RPBLK + wv;

    float c0 = 0.f, c1 = 0.f;
    char* const hb = (char*)h_lds;

    __syncthreads();   // tokens + h staged

    // P prefetch prologue: steps 0..2; tkR = token for step 3
    uint pA[4], pB[4], pC[4], pD[4];
    float4 qA, qB, qC, qD;
    int tkR;
    {
        int tk0 = xtok[wv][0];
        int tk1 = xtok[wv][1];
        int tk2 = xtok[wv][2];
        tkR = xtok[wv][3];
        const _Float16* p0 = P + (size_t)tk0 * G4;
        const _Float16* p1 = P + (size_t)tk1 * G4;
        const _Float16* p2 = P + (size_t)tk2 * G4;
        #pragma unroll
        for (int g = 0; g < 4; ++g) {
            pA[g] = *(const uint*)&p0[g * 128 + 2 * lane];
            pB[g] = *(const uint*)&p1[g * 128 + 2 * lane];
            pC[g] = *(const uint*)&p2[g * 128 + 2 * lane];
        }
        qA = *(const float4*)&Psum[(size_t)tk0 * 4];
        qB = *(const float4*)&Psum[(size_t)tk1 * 4];
        qC = *(const float4*)&Psum[(size_t)tk2 * 4];
    }

    for (int t = 0; t < Tt; t += 4) {
        LSTM_STEP(t,     pA, qA, pD, qD)
        LSTM_STEP(t + 1, pB, qB, pA, qA)
        LSTM_STEP(t + 2, pC, qC, pB, qB)
        LSTM_STEP(t + 3, pD, qD, pC, qC)
    }
}

// ---------------------------------------------------------------------------
extern "C" void kernel_launch(void* const* d_in, const int* in_sizes, int n_in,
                              void* d_out, int out_size, void* d_ws, size_t ws_size,
                              hipStream_t stream) {
    const int*   x      = (const int*)d_in[0];
    const float* embed  = (const float*)d_in[1];
    const float* W      = (const float*)d_in[2];
    const float* gains  = (const float*)d_in[3];
    const float* shifts = (const float*)d_in[4];
    float* out = (float*)d_out;

    _Float16* P    = (_Float16*)d_ws;                      // 51.2 MB
    float*    Psum = (float*)((char*)d_ws + (size_t)Vv * G4 * 2);   // 800 KB
    float*    Wsum = (float*)((char*)Psum + (size_t)Vv * 4 * 4);    // 2 KB

    embed_proj_mfma<<<dim3(256), dim3(512), 0, stream>>>(embed, W, P);
    wsum_kernel<<<dim3(1), dim3(128), 0, stream>>>(W, Wsum);
    psum_kernel<<<dim3(412), dim3(256), 0, stream>>>(P, Psum);
    lstm_mfma6<<<dim3(LBLK), dim3(256), 0, stream>>>(P, Psum, Wsum, W, x,
                                                     gains, shifts, out);
}